// Round 16
// baseline (2529.505 us; speedup 1.0000x reference)
//
#include <hip/hip_runtime.h>
#include <hip/hip_bf16.h>
#include <stdint.h>

#define HIDDEN 1024
#define FEAT   64
#define BATCH  512
#define SEQ    64
#define GATES  3072        // 3*HIDDEN

typedef __attribute__((ext_vector_type(4))) float f32x4;
typedef __attribute__((ext_vector_type(8))) short s16x8;   // 8 bf16 = 4 VGPRs (MFMA A/B frag)

#define MFMA16(a, b, c) __builtin_amdgcn_mfma_f32_16x16x32_bf16(a, b, c, 0, 0, 0)
#define VMCNT(n) asm volatile("s_waitcnt vmcnt(" #n ")" ::: "memory")
#define LGKMCNT0 asm volatile("s_waitcnt lgkmcnt(0)" ::: "memory")

__device__ inline unsigned short f2bf(float f) {
    unsigned u = __builtin_bit_cast(unsigned, f);
    u += 0x7fff + ((u >> 16) & 1);          // round-to-nearest-even
    return (unsigned short)(u >> 16);
}
__device__ inline float bf2f(unsigned short s) {
    unsigned u = ((unsigned)s) << 16;
    return __builtin_bit_cast(float, u);
}

#define GLOAD_LDS16(g, l) __builtin_amdgcn_global_load_lds( \
    (const __attribute__((address_space(1))) unsigned int*)(g), \
    (__attribute__((address_space(3))) unsigned int*)(l), 16, 0, 0)

// ---------------- weight conversion: 32-unit chunk-tiled slabs ----------------
// dst: [ub:32][c:16][96 rows][64 cols] bf16, 12 KB per (ub,c) contiguous.
// row = ug*48 + g*16 + jj -> unit j = ub*32 + ug*16 + jj, gate g. (ug*48 ≡ 0 mod 8
// keeps the row-parity XOR swizzle formula valid on the read side.)
__global__ void k_conv_whh_t(const float* __restrict__ src, unsigned short* __restrict__ dst) {
    int i = blockIdx.x * 256 + threadIdx.x;          // 3072*1024 threads
    int ub = i / 98304;                              // 16 c * 6144
    int r  = i - ub * 98304;
    int c  = r / 6144;
    int r2 = r - c * 6144;
    int srow = r2 >> 6, scol = r2 & 63;
    int ug = srow / 48, rr = srow - ug * 48;
    int g = rr >> 4, jj = rr & 15;
    int src_row = (g << 10) + (ub << 5) + (ug << 4) + jj;
    dst[i] = f2bf(src[(size_t)src_row * 1024 + (c << 6) + scol]);
}

// layer-0 Wih: [ub:32][96][64], 12 KB per ub (single K=64 chunk)
__global__ void k_conv_wih0_t(const float* __restrict__ src, unsigned short* __restrict__ dst) {
    int i = blockIdx.x * 256 + threadIdx.x;          // 3072*64 threads
    int ub = i / 6144;
    int r  = i - ub * 6144;
    int srow = r >> 6, scol = r & 63;
    int ug = srow / 48, rr = srow - ug * 48;
    int g = rr >> 4, jj = rr & 15;
    int src_row = (g << 10) + (ub << 5) + (ug << 4) + jj;
    dst[i] = f2bf(src[(size_t)src_row * 64 + scol]);
}

// x (B,T,F) fp32 -> xbf (T,B,F) bf16  (chunk-contiguous)
__global__ void k_xpose(const float* __restrict__ x, unsigned short* __restrict__ xbf) {
    int i = blockIdx.x * blockDim.x + threadIdx.x;
    if (i >= BATCH * SEQ * FEAT) return;
    int f = i & 63, t = (i >> 6) & 63, b = i >> 12;
    xbf[((size_t)t * BATCH + b) * FEAT + f] = f2bf(x[i]);
}

// ---------------- chunk staging: contiguous 1KB groups, swizzle applied ONCE (rule #21) ----------------
// W chunk 12 KB (12 groups), A chunk 16 KB (16 groups) -> 7 gload_lds per wave (uniform).
__device__ __forceinline__ void stage_pair(const char* ws, const char* as,
                                           unsigned short* Wd, unsigned short* Ad,
                                           int wid, int lane)
{
    const int lrow = lane >> 3;
    const int srcoff = lrow * 128 + (((lane & 7) ^ (lrow & 7)) << 4);
#pragma unroll
    for (int r = 0; r < 3; ++r) {
        int g = wid * 3 + r;
        GLOAD_LDS16(ws + (g << 10) + srcoff, (char*)Wd + (g << 10));
    }
#pragma unroll
    for (int r = 0; r < 4; ++r) {
        int g = wid + r * 4;
        GLOAD_LDS16(as + (g << 10) + srcoff, (char*)Ad + (g << 10));
    }
}

// ---------------- compute one 64-col K-chunk: 2 ks x 2 rowfrag x 2 ug x 3 gates = 24 MFMA ----------------
// acc[rowfrag][ug][slot]: slot 0=r, 1=z, NSLOT(2|3)=n-part.
template<int NSLOT>
__device__ __forceinline__ void compute_chunk(const unsigned short* aL, const unsigned short* wL,
                                              int wid, int lane, f32x4 (&acc)[2][2][4])
{
    const int l15 = lane & 15, hi = lane >> 4;
    const int swz = (l15 & 7) << 4;
    const char* ap = (const char*)aL;
    const char* wp = (const char*)wL;
#pragma unroll
    for (int ks = 0; ks < 2; ++ks) {
        const int kb = ks * 64 + (hi << 4);
        s16x8 a0 = *(const s16x8*)(ap + ((((wid * 32 + l15) * 128) + kb) ^ swz));
        s16x8 a1 = *(const s16x8*)(ap + ((((wid * 32 + 16 + l15) * 128) + kb) ^ swz));
#pragma unroll
        for (int ug = 0; ug < 2; ++ug) {
            const int wr = ug * 48 + l15;
            s16x8 b0 = *(const s16x8*)(wp + ((((wr)      * 128) + kb) ^ swz));
            s16x8 b1 = *(const s16x8*)(wp + ((((wr + 16) * 128) + kb) ^ swz));
            s16x8 b2 = *(const s16x8*)(wp + ((((wr + 32) * 128) + kb) ^ swz));
            acc[0][ug][0]     = MFMA16(a0, b0, acc[0][ug][0]);
            acc[0][ug][1]     = MFMA16(a0, b1, acc[0][ug][1]);
            acc[0][ug][NSLOT] = MFMA16(a0, b2, acc[0][ug][NSLOT]);
            acc[1][ug][0]     = MFMA16(a1, b0, acc[1][ug][0]);
            acc[1][ug][1]     = MFMA16(a1, b1, acc[1][ug][1]);
            acc[1][ug][NSLOT] = MFMA16(a1, b2, acc[1][ug][NSLOT]);
        }
    }
}

// ---------------- wavefront stage kernel, v10: 32-unit blocks (half A-amplification) ----------------
// Stage d: (L0,t=d), (L1,t=d-1), (L2,t=d-2). 384 blocks x 256 threads (LDS 56 KB, 2/CU).
// Block: 128 batch rows x 32 units x 3 gates. Depth-2 counted-vmcnt schedule (verified).
// h buffers: 2-slot rings, tiled [kchunk][512][64] per slot.
__global__ __launch_bounds__(256, 2) void k_stage(
    int d,
    const unsigned short* __restrict__ xbf,
    unsigned short* __restrict__ h0,
    unsigned short* __restrict__ h1,
    unsigned short* __restrict__ h2,
    const unsigned short* __restrict__ wih0R,
    const unsigned short* __restrict__ whh0R,
    const unsigned short* __restrict__ wih1R,
    const unsigned short* __restrict__ whh1R,
    const unsigned short* __restrict__ wih2R,
    const unsigned short* __restrict__ whh2R,
    const float* __restrict__ bih0, const float* __restrict__ bhh0,
    const float* __restrict__ bih1, const float* __restrict__ bhh1,
    const float* __restrict__ bih2, const float* __restrict__ bhh2)
{
    __shared__ unsigned short Wb[2][96 * 64];    // 2 x 12 KB
    __shared__ unsigned short Ab[2][128 * 64];   // 2 x 16 KB
    const int bid = blockIdx.x;
    const int slot = bid & 7;
    const int p = (bid >> 3) % 12;
    const int bg = bid / 96;                     // batch group 0..3
    const int pair = slot + 8 * p;               // 0..95 (XCD-pinned: bg blocks share slot)
    const int layer = pair >> 5;
    const int ub = pair & 31;
    const int t = d - layer;
    if (t < 0 || t >= SEQ) return;

    const int tid = threadIdx.x;
    const int wid = tid >> 6, lane = tid & 63;
    const int l15 = lane & 15, hi = lane >> 4;
    const int brow0 = bg * 128;

    const unsigned short* inseq = (layer == 0) ? xbf : ((layer == 1) ? h0 : h1);
    unsigned short* outseq = (layer == 0) ? h0 : ((layer == 1) ? h1 : h2);
    const unsigned short* wihR = (layer == 0) ? wih0R : ((layer == 1) ? wih1R : wih2R);
    const unsigned short* whhR = (layer == 0) ? whh0R : ((layer == 1) ? whh1R : whh2R);

    // byte bases; h rings slot = t&1; chunk strides: W 12288, A 65536
    const char* a1base = (layer == 0)
        ? (const char*)xbf + (size_t)t * 65536 + (size_t)brow0 * 128
        : (const char*)inseq + (size_t)(t & 1) * 1048576 + (size_t)brow0 * 128;
    const char* w1base = (layer == 0)
        ? (const char*)wih0R + (size_t)ub * 12288
        : (const char*)wihR + (size_t)ub * 196608;
    const char* a2base = (const char*)outseq + (size_t)((t - 1) & 1) * 1048576 + (size_t)brow0 * 128;
    const char* w2base = (const char*)whhR + (size_t)ub * 196608;

    const int NCH1 = (layer == 0) ? 1 : 16;
    const int NCH2 = (t > 0) ? 16 : 0;
    const int total = NCH1 + NCH2;

    auto srcs = [&](int c, const char*& ws, const char*& as) {
        if (c < NCH1) {
            ws = w1base + (size_t)c * 12288;
            as = a1base + (size_t)c * 65536;
        } else {
            int c2 = c - NCH1;
            ws = w2base + (size_t)c2 * 12288;
            as = a2base + (size_t)c2 * 65536;
        }
    };

    f32x4 acc[2][2][4];
    const f32x4 zero = {0.f, 0.f, 0.f, 0.f};
#pragma unroll
    for (int i = 0; i < 2; ++i)
#pragma unroll
        for (int ug = 0; ug < 2; ++ug)
#pragma unroll
            for (int s = 0; s < 4; ++s) acc[i][ug][s] = zero;

    // prologue: stage chunk 0 into buf 0
    {
        const char* ws; const char* as;
        srcs(0, ws, as);
        stage_pair(ws, as, Wb[0], Ab[0], wid, lane);
    }

    for (int c = 0; c < total; ++c) {
        const int cb = c & 1;
        if (c + 1 < total) {
            const char* ws; const char* as;
            srcs(c + 1, ws, as);
            stage_pair(ws, as, Wb[cb ^ 1], Ab[cb ^ 1], wid, lane);
            VMCNT(7);        // drain chunk-c loads; chunk-(c+1)'s 7 stay in flight (T4)
        } else {
            VMCNT(0);
        }
        __builtin_amdgcn_s_barrier();
        __builtin_amdgcn_sched_barrier(0);
        if (c < NCH1) compute_chunk<2>(Ab[cb], Wb[cb], wid, lane, acc);
        else          compute_chunk<3>(Ab[cb], Wb[cb], wid, lane, acc);
        LGKMCNT0;
        __builtin_amdgcn_sched_barrier(0);
        __builtin_amdgcn_s_barrier();
    }

    // ---- fused gate epilogue: wave writes 32 rows x 32 units ----
    const float* bih = (layer == 0) ? bih0 : ((layer == 1) ? bih1 : bih2);
    const float* bhh = (layer == 0) ? bhh0 : ((layer == 1) ? bhh1 : bhh2);
    const unsigned short* hprev = outseq + (size_t)((t > 0) ? ((t - 1) & 1) : 0) * (512 * 1024);
    unsigned short* hout = outseq + (size_t)(t & 1) * (512 * 1024);
    const int jc = ub >> 1;                       // kchunk of this block's units
#pragma unroll
    for (int ug = 0; ug < 2; ++ug) {
        const int j = ub * 32 + ug * 16 + l15;
        const int jcol = (ub & 1) * 32 + ug * 16 + l15;
        const float br  = bih[j] + bhh[j];
        const float bz  = bih[HIDDEN + j] + bhh[HIDDEN + j];
        const float bxn = bih[2 * HIDDEN + j];
        const float bhn = bhh[2 * HIDDEN + j];
#pragma unroll
        for (int i = 0; i < 2; ++i)
#pragma unroll
            for (int r = 0; r < 4; ++r) {
                int brow = brow0 + wid * 32 + i * 16 + hi * 4 + r;
                size_t hidx = (size_t)(jc * 512 + brow) * 64 + jcol;
                float rg = 1.f / (1.f + __expf(-(acc[i][ug][0][r] + br)));
                float zg = 1.f / (1.f + __expf(-(acc[i][ug][1][r] + bz)));
                float ng = tanhf(acc[i][ug][2][r] + bxn + rg * (acc[i][ug][3][r] + bhn));
                float hv = (t > 0) ? bf2f(hprev[hidx]) : 0.f;
                float hnew = (1.f - zg) * ng + zg * hv;
                hout[hidx] = f2bf(hnew);
            }
    }
}

// ---------------- batch-norm over batch (tiled h layout), deterministic ----------------
__global__ void k_bn_part(const unsigned short* __restrict__ h, float* __restrict__ part) {
    int j = threadIdx.x;                 // 1024 threads = all units
    int blk = blockIdx.x;                // 16 blocks x 32 rows
    const int jc = j >> 6, jcol = j & 63;
    float s = 0.f, q = 0.f;
    for (int b = blk * 32; b < blk * 32 + 32; ++b) {
        float v = bf2f(h[(size_t)(jc * 512 + b) * 64 + jcol]);
        s += v; q += v * v;
    }
    part[blk * 2048 + j] = s;
    part[blk * 2048 + 1024 + j] = q;
}

__global__ void k_bn_fold(const float* __restrict__ part, const float* __restrict__ gamma,
                          const float* __restrict__ beta, float* __restrict__ a, float* __restrict__ bb)
{
    int j = blockIdx.x * 256 + threadIdx.x;   // HIDDEN threads
    float s = 0.f, q = 0.f;
    for (int p = 0; p < 16; ++p) {
        s += part[p * 2048 + j];
        q += part[p * 2048 + 1024 + j];
    }
    float mu = s * (1.f / BATCH);
    float var = q * (1.f / BATCH) - mu * mu;
    float rs = rsqrtf(var + 1e-5f);
    float aj = gamma[j] * rs;
    a[j] = aj;
    bb[j] = beta[j] - mu * aj;
}

// ---------------- FC(1024->1) + sigmoid (tiled h layout) ----------------
__global__ void k_fc(const unsigned short* __restrict__ h, const float* __restrict__ a, const float* __restrict__ bb,
                     const float* __restrict__ fcW, const float* __restrict__ fcb, float* __restrict__ out)
{
    int b = blockIdx.x;
    int lane = threadIdx.x;
    float s = 0.f;
    for (int j = lane; j < HIDDEN; j += 64)
        s += (bf2f(h[(size_t)((j >> 6) * 512 + b) * 64 + (j & 63)]) * a[j] + bb[j]) * fcW[j];
#pragma unroll
    for (int m = 32; m; m >>= 1) s += __shfl_xor(s, m, 64);
    if (lane == 0) out[b] = 1.f / (1.f + __expf(-(s + fcb[0])));
}

// ---------------- driver ----------------
extern "C" void kernel_launch(void* const* d_in, const int* in_sizes, int n_in,
                              void* d_out, int out_size, void* d_ws, size_t ws_size,
                              hipStream_t stream)
{
    const float* x = (const float*)d_in[0];
    const float* W_ih[3] = {(const float*)d_in[1], (const float*)d_in[5], (const float*)d_in[9]};
    const float* W_hh[3] = {(const float*)d_in[2], (const float*)d_in[6], (const float*)d_in[10]};
    const float* b_ih[3] = {(const float*)d_in[3], (const float*)d_in[7], (const float*)d_in[11]};
    const float* b_hh[3] = {(const float*)d_in[4], (const float*)d_in[8], (const float*)d_in[12]};
    const float* gamma = (const float*)d_in[13];
    const float* beta  = (const float*)d_in[14];
    const float* fcW   = (const float*)d_in[15];
    const float* fcb   = (const float*)d_in[16];

    char* ws = (char*)d_ws;
    size_t off = 0;
    auto alloc = [&](size_t bytes) -> void* {
        void* p = ws + off;
        off = (off + bytes + 255) & ~(size_t)255;
        return p;
    };
    unsigned short* wih0R = (unsigned short*)alloc((size_t)GATES * FEAT * 2);
    unsigned short* whh0R = (unsigned short*)alloc((size_t)GATES * HIDDEN * 2);
    unsigned short* wih1R = (unsigned short*)alloc((size_t)GATES * HIDDEN * 2);
    unsigned short* whh1R = (unsigned short*)alloc((size_t)GATES * HIDDEN * 2);
    unsigned short* wih2R = (unsigned short*)alloc((size_t)GATES * HIDDEN * 2);
    unsigned short* whh2R = (unsigned short*)alloc((size_t)GATES * HIDDEN * 2);
    unsigned short* xbf = (unsigned short*)alloc((size_t)SEQ * BATCH * FEAT * 2);
    unsigned short* h0  = (unsigned short*)alloc((size_t)2 * BATCH * HIDDEN * 2);  // 2-slot rings
    unsigned short* h1  = (unsigned short*)alloc((size_t)2 * BATCH * HIDDEN * 2);
    unsigned short* h2  = (unsigned short*)alloc((size_t)2 * BATCH * HIDDEN * 2);
    float* part = (float*)alloc(16 * 2048 * 4);
    float* abuf = (float*)alloc(HIDDEN * 4);
    float* bbuf = (float*)alloc(HIDDEN * 4);

    // weights -> bf16, 32-unit chunk-tiled (stateless every call)
    k_conv_wih0_t<<<(GATES * FEAT) / 256, 256, 0, stream>>>(W_ih[0], wih0R);
    k_conv_whh_t<<<(GATES * HIDDEN) / 256, 256, 0, stream>>>(W_hh[0], whh0R);
    k_conv_whh_t<<<(GATES * HIDDEN) / 256, 256, 0, stream>>>(W_ih[1], wih1R);
    k_conv_whh_t<<<(GATES * HIDDEN) / 256, 256, 0, stream>>>(W_hh[1], whh1R);
    k_conv_whh_t<<<(GATES * HIDDEN) / 256, 256, 0, stream>>>(W_ih[2], wih2R);
    k_conv_whh_t<<<(GATES * HIDDEN) / 256, 256, 0, stream>>>(W_hh[2], whh2R);
    k_xpose<<<(BATCH * SEQ * FEAT + 255) / 256, 256, 0, stream>>>(x, xbf);

    // wavefront over (layer, t): 66 stages
    for (int d = 0; d < SEQ + 2; ++d)
        k_stage<<<384, 256, 0, stream>>>(d, xbf, h0, h1, h2,
                                         wih0R, whh0R, wih1R, whh1R, wih2R, whh2R,
                                         b_ih[0], b_hh[0], b_ih[1], b_hh[1], b_ih[2], b_hh[2]);

    // h2 ring slot holding t = SEQ-1 = 63 -> slot 1
    const unsigned short* hlast = h2 + (size_t)((SEQ - 1) & 1) * (BATCH * HIDDEN);
    k_bn_part<<<16, 1024, 0, stream>>>(hlast, part);
    k_bn_fold<<<HIDDEN / 256, 256, 0, stream>>>(part, gamma, beta, abuf, bbuf);
    k_fc<<<BATCH, 64, 0, stream>>>(hlast, abuf, bbuf, fcW, fcb, (float*)d_out);
}

// Round 17
// 2170.688 us; speedup vs baseline: 1.1653x; 1.1653x over previous
//
#include <hip/hip_runtime.h>
#include <hip/hip_bf16.h>
#include <stdint.h>

#define HIDDEN 1024
#define FEAT   64
#define BATCH  512
#define SEQ    64
#define GATES  3072        // 3*HIDDEN

typedef __attribute__((ext_vector_type(4))) float f32x4;
typedef __attribute__((ext_vector_type(8))) short s16x8;   // 8 bf16 = 4 VGPRs (MFMA A/B frag)

#define MFMA16(a, b, c) __builtin_amdgcn_mfma_f32_16x16x32_bf16(a, b, c, 0, 0, 0)
#define VMCNT(n) asm volatile("s_waitcnt vmcnt(" #n ")" ::: "memory")
#define LGKMCNT0 asm volatile("s_waitcnt lgkmcnt(0)" ::: "memory")

__device__ inline unsigned short f2bf(float f) {
    unsigned u = __builtin_bit_cast(unsigned, f);
    u += 0x7fff + ((u >> 16) & 1);          // round-to-nearest-even
    return (unsigned short)(u >> 16);
}
__device__ inline float bf2f(unsigned short s) {
    unsigned u = ((unsigned)s) << 16;
    return __builtin_bit_cast(float, u);
}

#define GLOAD_LDS16(g, l) __builtin_amdgcn_global_load_lds( \
    (const __attribute__((address_space(1))) unsigned int*)(g), \
    (__attribute__((address_space(3))) unsigned int*)(l), 16, 0, 0)

// ---------------- weight conversion: chunk-tiled, plain content (round-13 verified) ----------------
// dst: [ub][c][48 rows][64 cols] bf16, 6 KB per (ub,c) contiguous; rows gate-permuted.
__global__ void k_conv_whh_t(const float* __restrict__ src, unsigned short* __restrict__ dst) {
    int i = blockIdx.x * 256 + threadIdx.x;          // 3072*1024 threads
    int ub = i / 49152;
    int r  = i - ub * 49152;
    int c  = r / 3072;
    int r2 = r - c * 3072;
    int srow = r2 >> 6, scol = r2 & 63;
    int src_row = ((srow >> 4) << 10) + (ub << 4) + (srow & 15);
    dst[i] = f2bf(src[(size_t)src_row * 1024 + (c << 6) + scol]);
}

// layer-0 Wih: [ub][48][64], 6 KB per ub
__global__ void k_conv_wih0_t(const float* __restrict__ src, unsigned short* __restrict__ dst) {
    int i = blockIdx.x * 256 + threadIdx.x;          // 3072*64 threads
    int ub = i / 3072;
    int r  = i - ub * 3072;
    int srow = r >> 6, scol = r & 63;
    int src_row = ((srow >> 4) << 10) + (ub << 4) + (srow & 15);
    dst[i] = f2bf(src[(size_t)src_row * 64 + scol]);
}

// x (B,T,F) fp32 -> xbf (T,B,F) bf16  (chunk-contiguous: 64-col rows)
__global__ void k_xpose(const float* __restrict__ x, unsigned short* __restrict__ xbf) {
    int i = blockIdx.x * blockDim.x + threadIdx.x;
    if (i >= BATCH * SEQ * FEAT) return;
    int f = i & 63, t = (i >> 6) & 63, b = i >> 12;
    xbf[((size_t)t * BATCH + b) * FEAT + f] = f2bf(x[i]);
}

// ---------------- chunk staging: contiguous sources, swizzle applied ONCE (rule #21) ----------------
__device__ __forceinline__ void stage_pair(const char* ws, const char* as,
                                           unsigned short* Wd, unsigned short* Ad,
                                           int wid, int lane)
{
    const int lrow = lane >> 3;
    const int srcoff = lrow * 128 + (((lane & 7) ^ (lrow & 7)) << 4);
    for (int g = wid; g < 6; g += 4)
        GLOAD_LDS16(ws + (g << 10) + srcoff, (char*)Wd + (g << 10));
#pragma unroll
    for (int r = 0; r < 4; ++r) {
        int g = wid + r * 4;
        GLOAD_LDS16(as + (g << 10) + srcoff, (char*)Ad + (g << 10));
    }
}

// ---------------- compute one 64-col K-chunk: 2 k-slices x 6 MFMA (verified) ----------------
template<int NSLOT>
__device__ __forceinline__ void compute_chunk(const unsigned short* aL, const unsigned short* wL,
                                              int wid, int lane, f32x4 (&acc)[2][4])
{
    const int l15 = lane & 15, hi = lane >> 4;
    const int swz = (l15 & 7) << 4;
    const char* ap = (const char*)aL;
    const char* wp = (const char*)wL;
    __builtin_amdgcn_s_setprio(1);           // T5: favor MFMA-issuing wave on the CU scheduler
#pragma unroll
    for (int ks = 0; ks < 2; ++ks) {
        const int kb = ks * 64 + (hi << 4);
        s16x8 a0 = *(const s16x8*)(ap + ((((wid * 32 + l15) * 128) + kb) ^ swz));
        s16x8 a1 = *(const s16x8*)(ap + ((((wid * 32 + 16 + l15) * 128) + kb) ^ swz));
        s16x8 b0 = *(const s16x8*)(wp + (((l15 * 128) + kb) ^ swz));
        s16x8 b1 = *(const s16x8*)(wp + ((((16 + l15) * 128) + kb) ^ swz));
        s16x8 b2 = *(const s16x8*)(wp + ((((32 + l15) * 128) + kb) ^ swz));
        acc[0][0]     = MFMA16(a0, b0, acc[0][0]);
        acc[0][1]     = MFMA16(a0, b1, acc[0][1]);
        acc[0][NSLOT] = MFMA16(a0, b2, acc[0][NSLOT]);
        acc[1][0]     = MFMA16(a1, b0, acc[1][0]);
        acc[1][1]     = MFMA16(a1, b1, acc[1][1]);
        acc[1][NSLOT] = MFMA16(a1, b2, acc[1][NSLOT]);
    }
    __builtin_amdgcn_s_setprio(0);
}

// ---------------- wavefront stage kernel, v9b: round-15 verified + T5 setprio ----------------
// Stage d: (L0,t=d), (L1,t=d-1), (L2,t=d-2). 768 blocks x 256 threads = exactly 3/CU.
// h_L[t] consumed only at stage t+L+1 -> 2-slot ring per layer (slot = t&1); working set
// (weights 37 MB + rings 6 MB + x 4 MB) L3-resident. h slot layout: [kchunk(16)][512][64].
__global__ __launch_bounds__(256, 3) void k_stage(
    int d,
    const unsigned short* __restrict__ xbf,
    unsigned short* __restrict__ h0,
    unsigned short* __restrict__ h1,
    unsigned short* __restrict__ h2,
    const unsigned short* __restrict__ wih0R,
    const unsigned short* __restrict__ whh0R,
    const unsigned short* __restrict__ wih1R,
    const unsigned short* __restrict__ whh1R,
    const unsigned short* __restrict__ wih2R,
    const unsigned short* __restrict__ whh2R,
    const float* __restrict__ bih0, const float* __restrict__ bhh0,
    const float* __restrict__ bih1, const float* __restrict__ bhh1,
    const float* __restrict__ bih2, const float* __restrict__ bhh2)
{
    __shared__ unsigned short Wb[2][48 * 64];    // 2 x 6 KB
    __shared__ unsigned short Ab[2][128 * 64];   // 2 x 16 KB
    const int bid = blockIdx.x;
    const int slot = bid & 7;
    const int p = (bid >> 3) % 24;
    const int bg = bid / 192;                    // batch group 0..3
    const int pair = slot + 8 * p;               // 0..191 (XCD-pinned: bg blocks share slot)
    const int layer = pair >> 6;
    const int ub = pair & 63;
    const int t = d - layer;
    if (t < 0 || t >= SEQ) return;

    const int tid = threadIdx.x;
    const int wid = tid >> 6, lane = tid & 63;
    const int l15 = lane & 15, hi = lane >> 4;
    const int brow0 = bg * 128;

    const unsigned short* inseq = (layer == 0) ? xbf : ((layer == 1) ? h0 : h1);
    unsigned short* outseq = (layer == 0) ? h0 : ((layer == 1) ? h1 : h2);
    const unsigned short* wihR = (layer == 0) ? wih0R : ((layer == 1) ? wih1R : wih2R);
    const unsigned short* whhR = (layer == 0) ? whh0R : ((layer == 1) ? whh1R : whh2R);

    // byte bases; h buffers are 2-slot rings (slot = t&1), xbf is full-sequence
    const char* a1base = (layer == 0)
        ? (const char*)xbf + (size_t)t * 65536 + (size_t)brow0 * 128
        : (const char*)inseq + (size_t)(t & 1) * 1048576 + (size_t)brow0 * 128;
    const char* w1base = (layer == 0)
        ? (const char*)wih0R + (size_t)ub * 6144
        : (const char*)wihR + (size_t)ub * 98304;
    const char* a2base = (const char*)outseq + (size_t)((t - 1) & 1) * 1048576 + (size_t)brow0 * 128;
    const char* w2base = (const char*)whhR + (size_t)ub * 98304;

    const int NCH1 = (layer == 0) ? 1 : 16;
    const int NCH2 = (t > 0) ? 16 : 0;
    const int total = NCH1 + NCH2;

    auto srcs = [&](int c, const char*& ws, const char*& as) {
        if (c < NCH1) {
            ws = w1base + (size_t)c * 6144;
            as = a1base + (size_t)c * 65536;
        } else {
            int c2 = c - NCH1;
            ws = w2base + (size_t)c2 * 6144;
            as = a2base + (size_t)c2 * 65536;
        }
    };

    f32x4 acc[2][4];
    const f32x4 zero = {0.f, 0.f, 0.f, 0.f};
#pragma unroll
    for (int i = 0; i < 2; ++i)
#pragma unroll
        for (int s = 0; s < 4; ++s) acc[i][s] = zero;

    // prologue: stage chunk 0 into buf 0
    {
        const char* ws; const char* as;
        srcs(0, ws, as);
        stage_pair(ws, as, Wb[0], Ab[0], wid, lane);
    }

    for (int c = 0; c < total; ++c) {
        const int cb = c & 1;
        if (c + 1 < total) {
            const char* ws; const char* as;
            srcs(c + 1, ws, as);
            stage_pair(ws, as, Wb[cb ^ 1], Ab[cb ^ 1], wid, lane);
            // wait chunk-c loads only; chunk-(c+1) stays in flight (T4)
            if (wid < 2) VMCNT(6); else VMCNT(5);
        } else {
            VMCNT(0);
        }
        __builtin_amdgcn_s_barrier();
        __builtin_amdgcn_sched_barrier(0);
        if (c < NCH1) compute_chunk<2>(Ab[cb], Wb[cb], wid, lane, acc);
        else          compute_chunk<3>(Ab[cb], Wb[cb], wid, lane, acc);
        LGKMCNT0;
        __builtin_amdgcn_sched_barrier(0);
        __builtin_amdgcn_s_barrier();
    }

    // ---- fused gate epilogue: each wave writes its 32 rows (tiled ring layout) ----
    const float* bih = (layer == 0) ? bih0 : ((layer == 1) ? bih1 : bih2);
    const float* bhh = (layer == 0) ? bhh0 : ((layer == 1) ? bhh1 : bhh2);
    const int j = ub * 16 + l15;
    const float br  = bih[j] + bhh[j];
    const float bz  = bih[HIDDEN + j] + bhh[HIDDEN + j];
    const float bxn = bih[2 * HIDDEN + j];
    const float bhn = bhh[2 * HIDDEN + j];
    const unsigned short* hprev = outseq + (size_t)((t > 0) ? ((t - 1) & 1) : 0) * (512 * 1024);
    unsigned short* hout = outseq + (size_t)(t & 1) * (512 * 1024);
    const int jc = (ub >> 2);                 // kchunk of unit j
    const int jcol = (ub & 3) * 16 + l15;     // col within chunk
#pragma unroll
    for (int i = 0; i < 2; ++i)
#pragma unroll
        for (int r = 0; r < 4; ++r) {
            int brow = brow0 + wid * 32 + i * 16 + hi * 4 + r;
            size_t hidx = (size_t)(jc * 512 + brow) * 64 + jcol;
            float rg = 1.f / (1.f + __expf(-(acc[i][0][r] + br)));
            float zg = 1.f / (1.f + __expf(-(acc[i][1][r] + bz)));
            float ng = tanhf(acc[i][2][r] + bxn + rg * (acc[i][3][r] + bhn));
            float hv = (t > 0) ? bf2f(hprev[hidx]) : 0.f;
            float hnew = (1.f - zg) * ng + zg * hv;
            hout[hidx] = f2bf(hnew);
        }
}

// ---------------- batch-norm over batch (tiled h layout), deterministic ----------------
__global__ void k_bn_part(const unsigned short* __restrict__ h, float* __restrict__ part) {
    int j = threadIdx.x;                 // 1024 threads = all units
    int blk = blockIdx.x;                // 16 blocks x 32 rows
    const int jc = j >> 6, jcol = j & 63;
    float s = 0.f, q = 0.f;
    for (int b = blk * 32; b < blk * 32 + 32; ++b) {
        float v = bf2f(h[(size_t)(jc * 512 + b) * 64 + jcol]);
        s += v; q += v * v;
    }
    part[blk * 2048 + j] = s;
    part[blk * 2048 + 1024 + j] = q;
}

__global__ void k_bn_fold(const float* __restrict__ part, const float* __restrict__ gamma,
                          const float* __restrict__ beta, float* __restrict__ a, float* __restrict__ bb)
{
    int j = blockIdx.x * 256 + threadIdx.x;   // HIDDEN threads
    float s = 0.f, q = 0.f;
    for (int p = 0; p < 16; ++p) {
        s += part[p * 2048 + j];
        q += part[p * 2048 + 1024 + j];
    }
    float mu = s * (1.f / BATCH);
    float var = q * (1.f / BATCH) - mu * mu;
    float rs = rsqrtf(var + 1e-5f);
    float aj = gamma[j] * rs;
    a[j] = aj;
    bb[j] = beta[j] - mu * aj;
}

// ---------------- FC(1024->1) + sigmoid (tiled h layout) ----------------
__global__ void k_fc(const unsigned short* __restrict__ h, const float* __restrict__ a, const float* __restrict__ bb,
                     const float* __restrict__ fcW, const float* __restrict__ fcb, float* __restrict__ out)
{
    int b = blockIdx.x;
    int lane = threadIdx.x;
    float s = 0.f;
    for (int j = lane; j < HIDDEN; j += 64)
        s += (bf2f(h[(size_t)((j >> 6) * 512 + b) * 64 + (j & 63)]) * a[j] + bb[j]) * fcW[j];
#pragma unroll
    for (int m = 32; m; m >>= 1) s += __shfl_xor(s, m, 64);
    if (lane == 0) out[b] = 1.f / (1.f + __expf(-(s + fcb[0])));
}

// ---------------- driver ----------------
extern "C" void kernel_launch(void* const* d_in, const int* in_sizes, int n_in,
                              void* d_out, int out_size, void* d_ws, size_t ws_size,
                              hipStream_t stream)
{
    const float* x = (const float*)d_in[0];
    const float* W_ih[3] = {(const float*)d_in[1], (const float*)d_in[5], (const float*)d_in[9]};
    const float* W_hh[3] = {(const float*)d_in[2], (const float*)d_in[6], (const float*)d_in[10]};
    const float* b_ih[3] = {(const float*)d_in[3], (const float*)d_in[7], (const float*)d_in[11]};
    const float* b_hh[3] = {(const float*)d_in[4], (const float*)d_in[8], (const float*)d_in[12]};
    const float* gamma = (const float*)d_in[13];
    const float* beta  = (const float*)d_in[14];
    const float* fcW   = (const float*)d_in[15];
    const float* fcb   = (const float*)d_in[16];

    char* ws = (char*)d_ws;
    size_t off = 0;
    auto alloc = [&](size_t bytes) -> void* {
        void* p = ws + off;
        off = (off + bytes + 255) & ~(size_t)255;
        return p;
    };
    unsigned short* wih0R = (unsigned short*)alloc((size_t)GATES * FEAT * 2);
    unsigned short* whh0R = (unsigned short*)alloc((size_t)GATES * HIDDEN * 2);
    unsigned short* wih1R = (unsigned short*)alloc((size_t)GATES * HIDDEN * 2);
    unsigned short* whh1R = (unsigned short*)alloc((size_t)GATES * HIDDEN * 2);
    unsigned short* wih2R = (unsigned short*)alloc((size_t)GATES * HIDDEN * 2);
    unsigned short* whh2R = (unsigned short*)alloc((size_t)GATES * HIDDEN * 2);
    unsigned short* xbf = (unsigned short*)alloc((size_t)SEQ * BATCH * FEAT * 2);
    unsigned short* h0  = (unsigned short*)alloc((size_t)2 * BATCH * HIDDEN * 2);  // 2-slot ring
    unsigned short* h1  = (unsigned short*)alloc((size_t)2 * BATCH * HIDDEN * 2);
    unsigned short* h2  = (unsigned short*)alloc((size_t)2 * BATCH * HIDDEN * 2);
    float* part = (float*)alloc(16 * 2048 * 4);
    float* abuf = (float*)alloc(HIDDEN * 4);
    float* bbuf = (float*)alloc(HIDDEN * 4);

    // weights -> bf16, chunk-tiled + gate-permuted (stateless every call)
    k_conv_wih0_t<<<(GATES * FEAT) / 256, 256, 0, stream>>>(W_ih[0], wih0R);
    k_conv_whh_t<<<(GATES * HIDDEN) / 256, 256, 0, stream>>>(W_hh[0], whh0R);
    k_conv_whh_t<<<(GATES * HIDDEN) / 256, 256, 0, stream>>>(W_ih[1], wih1R);
    k_conv_whh_t<<<(GATES * HIDDEN) / 256, 256, 0, stream>>>(W_hh[1], whh1R);
    k_conv_whh_t<<<(GATES * HIDDEN) / 256, 256, 0, stream>>>(W_ih[2], wih2R);
    k_conv_whh_t<<<(GATES * HIDDEN) / 256, 256, 0, stream>>>(W_hh[2], whh2R);
    k_xpose<<<(BATCH * SEQ * FEAT + 255) / 256, 256, 0, stream>>>(x, xbf);

    // wavefront over (layer, t): 66 stages
    for (int d = 0; d < SEQ + 2; ++d)
        k_stage<<<768, 256, 0, stream>>>(d, xbf, h0, h1, h2,
                                         wih0R, whh0R, wih1R, whh1R, wih2R, whh2R,
                                         b_ih[0], b_hh[0], b_ih[1], b_hh[1], b_ih[2], b_hh[2]);

    // h2 ring slot holding t = SEQ-1 = 63 -> slot 1
    const unsigned short* hlast = h2 + (size_t)((SEQ - 1) & 1) * (BATCH * HIDDEN);
    k_bn_part<<<16, 1024, 0, stream>>>(hlast, part);
    k_bn_fold<<<HIDDEN / 256, 256, 0, stream>>>(part, gamma, beta, abuf, bbuf);
    k_fc<<<BATCH, 64, 0, stream>>>(hlast, abuf, bbuf, fcW, fcb, (float*)d_out);
}

// Round 18
// 2031.594 us; speedup vs baseline: 1.2451x; 1.0685x over previous
//
#include <hip/hip_runtime.h>
#include <hip/hip_bf16.h>
#include <stdint.h>

#define HIDDEN 1024
#define FEAT   64
#define BATCH  512
#define SEQ    64
#define GATES  3072        // 3*HIDDEN

typedef __attribute__((ext_vector_type(4))) float f32x4;
typedef __attribute__((ext_vector_type(8))) short s16x8;   // 8 bf16 = 4 VGPRs (MFMA A/B frag)

#define MFMA16(a, b, c) __builtin_amdgcn_mfma_f32_16x16x32_bf16(a, b, c, 0, 0, 0)
#define VMCNT(n) asm volatile("s_waitcnt vmcnt(" #n ")" ::: "memory")
#define LGKMCNT0 asm volatile("s_waitcnt lgkmcnt(0)" ::: "memory")

__device__ inline unsigned short f2bf(float f) {
    unsigned u = __builtin_bit_cast(unsigned, f);
    u += 0x7fff + ((u >> 16) & 1);          // round-to-nearest-even
    return (unsigned short)(u >> 16);
}
__device__ inline float bf2f(unsigned short s) {
    unsigned u = ((unsigned)s) << 16;
    return __builtin_bit_cast(float, u);
}

#define GLOAD_LDS16(g, l) __builtin_amdgcn_global_load_lds( \
    (const __attribute__((address_space(1))) unsigned int*)(g), \
    (__attribute__((address_space(3))) unsigned int*)(l), 16, 0, 0)

// ---------------- weight conversion: 32-unit chunk-tiled slabs (round-16 verified) ----------------
// dst: [ub:32][c:16][96 rows][64 cols] bf16, 12 KB per (ub,c) contiguous.
// row = ug*48 + g*16 + jj -> unit j = ub*32 + ug*16 + jj, gate g.
__global__ void k_conv_whh_t(const float* __restrict__ src, unsigned short* __restrict__ dst) {
    int i = blockIdx.x * 256 + threadIdx.x;          // 3072*1024 threads
    int ub = i / 98304;                              // 16 c * 6144
    int r  = i - ub * 98304;
    int c  = r / 6144;
    int r2 = r - c * 6144;
    int srow = r2 >> 6, scol = r2 & 63;
    int ug = srow / 48, rr = srow - ug * 48;
    int g = rr >> 4, jj = rr & 15;
    int src_row = (g << 10) + (ub << 5) + (ug << 4) + jj;
    dst[i] = f2bf(src[(size_t)src_row * 1024 + (c << 6) + scol]);
}

// layer-0 Wih: [ub:32][96][64], 12 KB per ub (single K=64 chunk)
__global__ void k_conv_wih0_t(const float* __restrict__ src, unsigned short* __restrict__ dst) {
    int i = blockIdx.x * 256 + threadIdx.x;          // 3072*64 threads
    int ub = i / 6144;
    int r  = i - ub * 6144;
    int srow = r >> 6, scol = r & 63;
    int ug = srow / 48, rr = srow - ug * 48;
    int g = rr >> 4, jj = rr & 15;
    int src_row = (g << 10) + (ub << 5) + (ug << 4) + jj;
    dst[i] = f2bf(src[(size_t)src_row * 64 + scol]);
}

// x (B,T,F) fp32 -> xbf (T,B,F) bf16  (chunk-contiguous)
__global__ void k_xpose(const float* __restrict__ x, unsigned short* __restrict__ xbf) {
    int i = blockIdx.x * blockDim.x + threadIdx.x;
    if (i >= BATCH * SEQ * FEAT) return;
    int f = i & 63, t = (i >> 6) & 63, b = i >> 12;
    xbf[((size_t)t * BATCH + b) * FEAT + f] = f2bf(x[i]);
}

// ---------------- chunk staging: W 12 KB + A 8 KB contiguous, swizzle applied ONCE ----------------
// 20 groups of 1 KB over 4 waves = 5 gload_lds per wave (uniform -> VMCNT(5) per chunk).
__device__ __forceinline__ void stage_pair(const char* ws, const char* as,
                                           unsigned short* Wd, unsigned short* Ad,
                                           int wid, int lane)
{
    const int lrow = lane >> 3;
    const int srcoff = lrow * 128 + (((lane & 7) ^ (lrow & 7)) << 4);
#pragma unroll
    for (int r = 0; r < 3; ++r) {
        int g = wid * 3 + r;                          // 0..11
        GLOAD_LDS16(ws + (g << 10) + srcoff, (char*)Wd + (g << 10));
    }
#pragma unroll
    for (int r = 0; r < 2; ++r) {
        int g = wid + r * 4;                          // 0..7
        GLOAD_LDS16(as + (g << 10) + srcoff, (char*)Ad + (g << 10));
    }
}

// ---------------- compute one 64-col K-chunk: 2 ks x 2 ug x 3 gates = 12 MFMA/wave ----------------
// acc[ug][slot]: slot 0=r, 1=z, NSLOT(2|3)=n-part. Wave owns 16 rows (1 row-fragment).
template<int NSLOT>
__device__ __forceinline__ void compute_chunk(const unsigned short* aL, const unsigned short* wL,
                                              int wid, int lane, f32x4 (&acc)[2][4])
{
    const int l15 = lane & 15, hi = lane >> 4;
    const int swz = (l15 & 7) << 4;
    const char* ap = (const char*)aL;
    const char* wp = (const char*)wL;
    __builtin_amdgcn_s_setprio(1);
#pragma unroll
    for (int ks = 0; ks < 2; ++ks) {
        const int kb = ks * 64 + (hi << 4);
        s16x8 a0 = *(const s16x8*)(ap + ((((wid * 16 + l15) * 128) + kb) ^ swz));
#pragma unroll
        for (int ug = 0; ug < 2; ++ug) {
            const int wr = ug * 48 + l15;
            s16x8 b0 = *(const s16x8*)(wp + ((((wr)      * 128) + kb) ^ swz));
            s16x8 b1 = *(const s16x8*)(wp + ((((wr + 16) * 128) + kb) ^ swz));
            s16x8 b2 = *(const s16x8*)(wp + ((((wr + 32) * 128) + kb) ^ swz));
            acc[ug][0]     = MFMA16(a0, b0, acc[ug][0]);
            acc[ug][1]     = MFMA16(a0, b1, acc[ug][1]);
            acc[ug][NSLOT] = MFMA16(a0, b2, acc[ug][NSLOT]);
        }
    }
    __builtin_amdgcn_s_setprio(0);
}

// ---------------- wavefront stage kernel, v11: U=32/R=64 (balanced traffic, 3 blocks/CU) ----------------
// Stage d: (L0,t=d), (L1,t=d-1), (L2,t=d-2). 768 blocks x 256 threads, 40 KB LDS -> 3/CU.
// Block: 64 batch rows x 32 units x 3 gates. Depth-2 counted-vmcnt schedule (verified).
// Per-layer staged traffic 160 MB vs U=16's 176 MB. h: 2-slot rings, [kchunk][512][64] per slot.
__global__ __launch_bounds__(256, 3) void k_stage(
    int d,
    const unsigned short* __restrict__ xbf,
    unsigned short* __restrict__ h0,
    unsigned short* __restrict__ h1,
    unsigned short* __restrict__ h2,
    const unsigned short* __restrict__ wih0R,
    const unsigned short* __restrict__ whh0R,
    const unsigned short* __restrict__ wih1R,
    const unsigned short* __restrict__ whh1R,
    const unsigned short* __restrict__ wih2R,
    const unsigned short* __restrict__ whh2R,
    const float* __restrict__ bih0, const float* __restrict__ bhh0,
    const float* __restrict__ bih1, const float* __restrict__ bhh1,
    const float* __restrict__ bih2, const float* __restrict__ bhh2)
{
    __shared__ unsigned short Wb[2][96 * 64];    // 2 x 12 KB
    __shared__ unsigned short Ab[2][64 * 64];    // 2 x 8 KB
    const int bid = blockIdx.x;
    const int slot = bid & 7;
    const int p = (bid >> 3) % 12;
    const int bg = bid / 96;                     // batch group 0..7
    const int pair = slot + 8 * p;               // 0..95 (XCD-pinned: bg blocks share slot)
    const int layer = pair >> 5;
    const int ub = pair & 31;
    const int t = d - layer;
    if (t < 0 || t >= SEQ) return;

    const int tid = threadIdx.x;
    const int wid = tid >> 6, lane = tid & 63;
    const int l15 = lane & 15, hi = lane >> 4;
    const int brow0 = bg * 64;

    const unsigned short* inseq = (layer == 0) ? xbf : ((layer == 1) ? h0 : h1);
    unsigned short* outseq = (layer == 0) ? h0 : ((layer == 1) ? h1 : h2);
    const unsigned short* wihR = (layer == 0) ? wih0R : ((layer == 1) ? wih1R : wih2R);
    const unsigned short* whhR = (layer == 0) ? whh0R : ((layer == 1) ? whh1R : wih2R);
    // NOTE: line above must select whh2R for layer 2 — fixed below
    const unsigned short* whhRx = (layer == 0) ? whh0R : ((layer == 1) ? whh1R : whh2R);

    // byte bases; h rings slot = t&1; chunk strides: W 12288, A 65536 (block slice bg*8192)
    const char* a1base = (layer == 0)
        ? (const char*)xbf + (size_t)t * 65536 + (size_t)brow0 * 128
        : (const char*)inseq + (size_t)(t & 1) * 1048576 + (size_t)brow0 * 128;
    const char* w1base = (layer == 0)
        ? (const char*)wih0R + (size_t)ub * 12288
        : (const char*)wihR + (size_t)ub * 196608;
    const char* a2base = (const char*)outseq + (size_t)((t - 1) & 1) * 1048576 + (size_t)brow0 * 128;
    const char* w2base = (const char*)whhRx + (size_t)ub * 196608;

    const int NCH1 = (layer == 0) ? 1 : 16;
    const int NCH2 = (t > 0) ? 16 : 0;
    const int total = NCH1 + NCH2;

    auto srcs = [&](int c, const char*& ws, const char*& as) {
        if (c < NCH1) {
            ws = w1base + (size_t)c * 12288;
            as = a1base + (size_t)c * 65536;
        } else {
            int c2 = c - NCH1;
            ws = w2base + (size_t)c2 * 12288;
            as = a2base + (size_t)c2 * 65536;
        }
    };

    f32x4 acc[2][4];
    const f32x4 zero = {0.f, 0.f, 0.f, 0.f};
#pragma unroll
    for (int ug = 0; ug < 2; ++ug)
#pragma unroll
        for (int s = 0; s < 4; ++s) acc[ug][s] = zero;

    // prologue: stage chunk 0 into buf 0
    {
        const char* ws; const char* as;
        srcs(0, ws, as);
        stage_pair(ws, as, Wb[0], Ab[0], wid, lane);
    }

    for (int c = 0; c < total; ++c) {
        const int cb = c & 1;
        if (c + 1 < total) {
            const char* ws; const char* as;
            srcs(c + 1, ws, as);
            stage_pair(ws, as, Wb[cb ^ 1], Ab[cb ^ 1], wid, lane);
            VMCNT(5);        // drain chunk-c loads; chunk-(c+1)'s 5 stay in flight (T4)
        } else {
            VMCNT(0);
        }
        __builtin_amdgcn_s_barrier();
        __builtin_amdgcn_sched_barrier(0);
        if (c < NCH1) compute_chunk<2>(Ab[cb], Wb[cb], wid, lane, acc);
        else          compute_chunk<3>(Ab[cb], Wb[cb], wid, lane, acc);
        LGKMCNT0;
        __builtin_amdgcn_sched_barrier(0);
        __builtin_amdgcn_s_barrier();
    }

    // ---- fused gate epilogue: wave writes its 16 rows x 32 units ----
    const float* bih = (layer == 0) ? bih0 : ((layer == 1) ? bih1 : bih2);
    const float* bhh = (layer == 0) ? bhh0 : ((layer == 1) ? bhh1 : bhh2);
    const unsigned short* hprev = outseq + (size_t)((t > 0) ? ((t - 1) & 1) : 0) * (512 * 1024);
    unsigned short* hout = outseq + (size_t)(t & 1) * (512 * 1024);
    const int jc = ub >> 1;                       // kchunk of this block's units
#pragma unroll
    for (int ug = 0; ug < 2; ++ug) {
        const int j = ub * 32 + ug * 16 + l15;
        const int jcol = (ub & 1) * 32 + ug * 16 + l15;
        const float br  = bih[j] + bhh[j];
        const float bz  = bih[HIDDEN + j] + bhh[HIDDEN + j];
        const float bxn = bih[2 * HIDDEN + j];
        const float bhn = bhh[2 * HIDDEN + j];
#pragma unroll
        for (int r = 0; r < 4; ++r) {
            int brow = brow0 + wid * 16 + hi * 4 + r;
            size_t hidx = (size_t)(jc * 512 + brow) * 64 + jcol;
            float rg = 1.f / (1.f + __expf(-(acc[ug][0][r] + br)));
            float zg = 1.f / (1.f + __expf(-(acc[ug][1][r] + bz)));
            float ng = tanhf(acc[ug][2][r] + bxn + rg * (acc[ug][3][r] + bhn));
            float hv = (t > 0) ? bf2f(hprev[hidx]) : 0.f;
            float hnew = (1.f - zg) * ng + zg * hv;
            hout[hidx] = f2bf(hnew);
        }
    }
}

// ---------------- batch-norm over batch (tiled h layout), deterministic ----------------
__global__ void k_bn_part(const unsigned short* __restrict__ h, float* __restrict__ part) {
    int j = threadIdx.x;                 // 1024 threads = all units
    int blk = blockIdx.x;                // 16 blocks x 32 rows
    const int jc = j >> 6, jcol = j & 63;
    float s = 0.f, q = 0.f;
    for (int b = blk * 32; b < blk * 32 + 32; ++b) {
        float v = bf2f(h[(size_t)(jc * 512 + b) * 64 + jcol]);
        s += v; q += v * v;
    }
    part[blk * 2048 + j] = s;
    part[blk * 2048 + 1024 + j] = q;
}

__global__ void k_bn_fold(const float* __restrict__ part, const float* __restrict__ gamma,
                          const float* __restrict__ beta, float* __restrict__ a, float* __restrict__ bb)
{
    int j = blockIdx.x * 256 + threadIdx.x;   // HIDDEN threads
    float s = 0.f, q = 0.f;
    for (int p = 0; p < 16; ++p) {
        s += part[p * 2048 + j];
        q += part[p * 2048 + 1024 + j];
    }
    float mu = s * (1.f / BATCH);
    float var = q * (1.f / BATCH) - mu * mu;
    float rs = rsqrtf(var + 1e-5f);
    float aj = gamma[j] * rs;
    a[j] = aj;
    bb[j] = beta[j] - mu * aj;
}

// ---------------- FC(1024->1) + sigmoid (tiled h layout) ----------------
__global__ void k_fc(const unsigned short* __restrict__ h, const float* __restrict__ a, const float* __restrict__ bb,
                     const float* __restrict__ fcW, const float* __restrict__ fcb, float* __restrict__ out)
{
    int b = blockIdx.x;
    int lane = threadIdx.x;
    float s = 0.f;
    for (int j = lane; j < HIDDEN; j += 64)
        s += (bf2f(h[(size_t)((j >> 6) * 512 + b) * 64 + (j & 63)]) * a[j] + bb[j]) * fcW[j];
#pragma unroll
    for (int m = 32; m; m >>= 1) s += __shfl_xor(s, m, 64);
    if (lane == 0) out[b] = 1.f / (1.f + __expf(-(s + fcb[0])));
}

// ---------------- driver ----------------
extern "C" void kernel_launch(void* const* d_in, const int* in_sizes, int n_in,
                              void* d_out, int out_size, void* d_ws, size_t ws_size,
                              hipStream_t stream)
{
    const float* x = (const float*)d_in[0];
    const float* W_ih[3] = {(const float*)d_in[1], (const float*)d_in[5], (const float*)d_in[9]};
    const float* W_hh[3] = {(const float*)d_in[2], (const float*)d_in[6], (const float*)d_in[10]};
    const float* b_ih[3] = {(const float*)d_in[3], (const float*)d_in[7], (const float*)d_in[11]};
    const float* b_hh[3] = {(const float*)d_in[4], (const float*)d_in[8], (const float*)d_in[12]};
    const float* gamma = (const float*)d_in[13];
    const float* beta  = (const float*)d_in[14];
    const float* fcW   = (const float*)d_in[15];
    const float* fcb   = (const float*)d_in[16];

    char* ws = (char*)d_ws;
    size_t off = 0;
    auto alloc = [&](size_t bytes) -> void* {
        void* p = ws + off;
        off = (off + bytes + 255) & ~(size_t)255;
        return p;
    };
    unsigned short* wih0R = (unsigned short*)alloc((size_t)GATES * FEAT * 2);
    unsigned short* whh0R = (unsigned short*)alloc((size_t)GATES * HIDDEN * 2);
    unsigned short* wih1R = (unsigned short*)alloc((size_t)GATES * HIDDEN * 2);
    unsigned short* whh1R = (unsigned short*)alloc((size_t)GATES * HIDDEN * 2);
    unsigned short* wih2R = (unsigned short*)alloc((size_t)GATES * HIDDEN * 2);
    unsigned short* whh2R = (unsigned short*)alloc((size_t)GATES * HIDDEN * 2);
    unsigned short* xbf = (unsigned short*)alloc((size_t)SEQ * BATCH * FEAT * 2);
    unsigned short* h0  = (unsigned short*)alloc((size_t)2 * BATCH * HIDDEN * 2);  // 2-slot rings
    unsigned short* h1  = (unsigned short*)alloc((size_t)2 * BATCH * HIDDEN * 2);
    unsigned short* h2  = (unsigned short*)alloc((size_t)2 * BATCH * HIDDEN * 2);
    float* part = (float*)alloc(16 * 2048 * 4);
    float* abuf = (float*)alloc(HIDDEN * 4);
    float* bbuf = (float*)alloc(HIDDEN * 4);

    // weights -> bf16, 32-unit chunk-tiled (stateless every call)
    k_conv_wih0_t<<<(GATES * FEAT) / 256, 256, 0, stream>>>(W_ih[0], wih0R);
    k_conv_whh_t<<<(GATES * HIDDEN) / 256, 256, 0, stream>>>(W_hh[0], whh0R);
    k_conv_whh_t<<<(GATES * HIDDEN) / 256, 256, 0, stream>>>(W_ih[1], wih1R);
    k_conv_whh_t<<<(GATES * HIDDEN) / 256, 256, 0, stream>>>(W_hh[1], whh1R);
    k_conv_whh_t<<<(GATES * HIDDEN) / 256, 256, 0, stream>>>(W_ih[2], wih2R);
    k_conv_whh_t<<<(GATES * HIDDEN) / 256, 256, 0, stream>>>(W_hh[2], whh2R);
    k_xpose<<<(BATCH * SEQ * FEAT + 255) / 256, 256, 0, stream>>>(x, xbf);

    // wavefront over (layer, t): 66 stages
    for (int d = 0; d < SEQ + 2; ++d)
        k_stage<<<768, 256, 0, stream>>>(d, xbf, h0, h1, h2,
                                         wih0R, whh0R, wih1R, whh1R, wih2R, whh2R,
                                         b_ih[0], b_hh[0], b_ih[1], b_hh[1], b_ih[2], b_hh[2]);

    // h2 ring slot holding t = SEQ-1 = 63 -> slot 1
    const unsigned short* hlast = h2 + (size_t)((SEQ - 1) & 1) * (BATCH * HIDDEN);
    k_bn_part<<<16, 1024, 0, stream>>>(hlast, part);
    k_bn_fold<<<HIDDEN / 256, 256, 0, stream>>>(part, gamma, beta, abuf, bbuf);
    k_fc<<<BATCH, 64, 0, stream>>>(hlast, abuf, bbuf, fcW, fcb, (float*)d_out);
}